// Round 1
// baseline (865.309 us; speedup 1.0000x reference)
//
#include <hip/hip_runtime.h>
#include <hip/hip_bf16.h>
#include <stdint.h>

#define T_TOK 8192
#define K_IN  4096
#define O_OUT 6144
#define BSCL  128

typedef __attribute__((ext_vector_type(8))) short bf16x8;
typedef __attribute__((ext_vector_type(4))) float f32x4;

// ---------- helpers ----------

__device__ inline ushort f32_to_bf16_rne(float f) {
    uint32_t u = __float_as_uint(f);
    uint32_t r = (u + 0x7fffu + ((u >> 16) & 1u)) >> 16;
    return (ushort)r;
}

// fp8 e4m3 round-trip (RNE, saturating) of two floats -> two exact floats
__device__ inline void fp8_roundtrip2(float a, float b, float& ra, float& rb) {
    int p = __builtin_amdgcn_cvt_pk_fp8_f32(a, b, 0, false);
    ra = __builtin_amdgcn_cvt_f32_fp8(p, 0);
    rb = __builtin_amdgcn_cvt_f32_fp8(p, 1);
}

__device__ inline void load_lds_16(const void* g, void* l) {
    __builtin_amdgcn_global_load_lds(
        (const __attribute__((address_space(1))) unsigned int*)g,
        (__attribute__((address_space(3))) unsigned int*)l, 16, 0, 0);
}

// ---------- kernel 1: per-token dynamic fp8 quantization of x ----------
// one block per token row; writes x_fp8 as bf16 (exact) + per-token scale
__global__ __launch_bounds__(256) void quant_x(const float* __restrict__ x,
                                               ushort* __restrict__ xq,
                                               float* __restrict__ xscale) {
    const int t   = blockIdx.x;
    const int tid = threadIdx.x;
    const float4* row4 = (const float4*)(x + (size_t)t * K_IN);

    float4 v[4];
    float amax = 0.f;
#pragma unroll
    for (int j = 0; j < 4; ++j) {
        v[j] = row4[tid + j * 256];
        amax = fmaxf(amax, fmaxf(fmaxf(fabsf(v[j].x), fabsf(v[j].y)),
                                 fmaxf(fabsf(v[j].z), fabsf(v[j].w))));
    }
    // wave reduce (64 lanes)
#pragma unroll
    for (int off = 32; off > 0; off >>= 1)
        amax = fmaxf(amax, __shfl_down(amax, off, 64));
    __shared__ float red[4];
    if ((tid & 63) == 0) red[tid >> 6] = amax;
    __syncthreads();
    amax = fmaxf(fmaxf(red[0], red[1]), fmaxf(red[2], red[3]));

    const float scale = fmaxf(amax, 1e-12f) / 448.0f;  // matches ref: clip then /FP8_MAX
    if (tid == 0) xscale[t] = scale;

    ushort4* orow = (ushort4*)(xq + (size_t)t * K_IN);
#pragma unroll
    for (int j = 0; j < 4; ++j) {
        // correctly-rounded fp32 division matches jnp's x / x_scale
        float q0 = v[j].x / scale, q1 = v[j].y / scale;
        float q2 = v[j].z / scale, q3 = v[j].w / scale;
        float r0, r1, r2, r3;
        fp8_roundtrip2(q0, q1, r0, r1);
        fp8_roundtrip2(q2, q3, r2, r3);
        ushort4 o;
        // fp8 values are exactly representable in bf16 -> truncation is exact
        o.x = (ushort)(__float_as_uint(r0) >> 16);
        o.y = (ushort)(__float_as_uint(r1) >> 16);
        o.z = (ushort)(__float_as_uint(r2) >> 16);
        o.w = (ushort)(__float_as_uint(r3) >> 16);
        orow[tid + j * 256] = o;
    }
}

// ---------- kernel 2: block-wise dequant of W into bf16 ----------
__global__ __launch_bounds__(256) void dequant_w(const float* __restrict__ w,
                                                 const float* __restrict__ sinv,
                                                 ushort* __restrict__ wq) {
    const size_t idx = ((size_t)blockIdx.x * 256 + threadIdx.x) * 4;
    const int o = (int)(idx >> 12);        // / 4096
    const int i = (int)(idx & 4095);
    const float s = sinv[(o >> 7) * (K_IN / BSCL) + (i >> 7)];

    float4 v = *(const float4*)(w + idx);
    float r0, r1, r2, r3;
    fp8_roundtrip2(v.x, v.y, r0, r1);
    fp8_roundtrip2(v.z, v.w, r2, r3);
    ushort4 out;
    out.x = f32_to_bf16_rne(r0 * s);
    out.y = f32_to_bf16_rne(r1 * s);
    out.z = f32_to_bf16_rne(r2 * s);
    out.w = f32_to_bf16_rne(r3 * s);
    *(ushort4*)(wq + idx) = out;
}

// ---------- kernel 3: bf16 GEMM  C[t][o] = (A[t][:] . B[o][:]) * xscale[t] ----------
// A: [T][K] bf16 row-major, B: [O][K] bf16 row-major (B^T gemm).
// 128x128 tile / block (256 thr = 4 waves in 2x2, each wave 64x64 via 4x4 MFMA 16x16x32).
__global__ __launch_bounds__(256) void gemm_bt(const ushort* __restrict__ A,
                                               const ushort* __restrict__ B,
                                               const float* __restrict__ xscale,
                                               float* __restrict__ C) {
    constexpr int BM = 128, BN = 128, BK = 64;
    __shared__ ushort As[BM * BK];  // 16 KB, xor-swizzled 16B chunks
    __shared__ ushort Bs[BN * BK];  // 16 KB

    const int bn = blockIdx.x;          // o tile (48)
    const int bm = blockIdx.y;          // token tile (64)
    const int tid  = threadIdx.x;
    const int lane = tid & 63;
    const int wv   = tid >> 6;
    const int wm   = (wv >> 1) * 64;    // wave row offset in tile
    const int wn   = (wv & 1) * 64;     // wave col offset in tile

    const ushort* Abase = A + (size_t)(bm * BM) * K_IN;
    const ushort* Bbase = B + (size_t)(bn * BN) * K_IN;

    f32x4 acc[4][4] = {};

    for (int k0 = 0; k0 < K_IN; k0 += BK) {
        // stage 16 KB A + 16 KB B; chunk c -> row r=c/8, lds slot (c&7),
        // global kchunk = (c&7) ^ (r&7)  (xor swizzle kills bank conflicts)
#pragma unroll
        for (int s = 0; s < 4; ++s) {
            int c  = s * 256 + tid;
            int r  = c >> 3;
            int kc = (c & 7) ^ (r & 7);
            load_lds_16(Abase + (size_t)r * K_IN + k0 + kc * 8, &As[c * 8]);
        }
#pragma unroll
        for (int s = 0; s < 4; ++s) {
            int c  = s * 256 + tid;
            int r  = c >> 3;
            int kc = (c & 7) ^ (r & 7);
            load_lds_16(Bbase + (size_t)r * K_IN + k0 + kc * 8, &Bs[c * 8]);
        }
        __syncthreads();

#pragma unroll
        for (int ks = 0; ks < 2; ++ks) {
            bf16x8 a[4], b[4];
            const int ch = ks * 4 + (lane >> 4);   // 16B chunk within row
#pragma unroll
            for (int i = 0; i < 4; ++i) {
                int r = wm + i * 16 + (lane & 15);
                a[i] = *(const bf16x8*)&As[(r * 8 + (ch ^ (r & 7))) * 8];
            }
#pragma unroll
            for (int j = 0; j < 4; ++j) {
                int r = wn + j * 16 + (lane & 15);
                b[j] = *(const bf16x8*)&Bs[(r * 8 + (ch ^ (r & 7))) * 8];
            }
#pragma unroll
            for (int i = 0; i < 4; ++i)
#pragma unroll
                for (int j = 0; j < 4; ++j)
                    acc[i][j] = __builtin_amdgcn_mfma_f32_16x16x32_bf16(
                        a[i], b[j], acc[i][j], 0, 0, 0);
        }
        __syncthreads();
    }

    // epilogue: D row = (lane>>4)*4 + reg (token), col = lane&15 (o)
#pragma unroll
    for (int i = 0; i < 4; ++i) {
#pragma unroll
        for (int r = 0; r < 4; ++r) {
            int m_g = bm * BM + wm + i * 16 + (lane >> 4) * 4 + r;
            float xs = xscale[m_g];
            float* crow = C + (size_t)m_g * O_OUT + bn * BN + wn;
#pragma unroll
            for (int j = 0; j < 4; ++j)
                crow[j * 16 + (lane & 15)] = acc[i][j][r] * xs;
        }
    }
}

// ---------- launch ----------
extern "C" void kernel_launch(void* const* d_in, const int* in_sizes, int n_in,
                              void* d_out, int out_size, void* d_ws, size_t ws_size,
                              hipStream_t stream) {
    const float* x    = (const float*)d_in[0];
    const float* w    = (const float*)d_in[1];
    const float* sinv = (const float*)d_in[2];
    float* out = (float*)d_out;

    char* ws = (char*)d_ws;
    ushort* xq = (ushort*)ws;                                  // 64 MB
    ushort* wq = (ushort*)(ws + (size_t)T_TOK * K_IN * 2);     // 48 MB
    float* xscale = (float*)(ws + (size_t)T_TOK * K_IN * 2
                                + (size_t)O_OUT * K_IN * 2);   // 32 KB

    quant_x<<<T_TOK, 256, 0, stream>>>(x, xq, xscale);
    dequant_w<<<(O_OUT * K_IN) / (4 * 256), 256, 0, stream>>>(w, sinv, wq);
    dim3 grid(O_OUT / 128, T_TOK / 128);   // (48, 64)
    gemm_bt<<<grid, 256, 0, stream>>>(xq, wq, xscale, out);
}

// Round 2
// 640.082 us; speedup vs baseline: 1.3519x; 1.3519x over previous
//
#include <hip/hip_runtime.h>
#include <hip/hip_bf16.h>
#include <stdint.h>

#define T_TOK 8192
#define K_IN  4096
#define O_OUT 6144

typedef __attribute__((ext_vector_type(4))) float f32x4;
typedef __attribute__((ext_vector_type(8))) int i32x8;
typedef unsigned int uint32;

// ---------- helpers ----------

__device__ inline void load_lds_16(const void* g, void* l) {
    __builtin_amdgcn_global_load_lds(
        (const __attribute__((address_space(1))) unsigned int*)g,
        (__attribute__((address_space(3))) unsigned int*)l, 16, 0, 0);
}

// pack 4 floats -> 4 fp8 e4m3 bytes (RNE, saturating), byte i = input i
__device__ inline int pack4_fp8(float a, float b, float c, float d) {
    int r = __builtin_amdgcn_cvt_pk_fp8_f32(a, b, 0, false);  // bytes 0,1
    r = __builtin_amdgcn_cvt_pk_fp8_f32(c, d, r, true);       // bytes 2,3
    return r;
}

// ---------- kernel 1: per-token dynamic fp8 quantization of x ----------
__global__ __launch_bounds__(256) void quant_x(const float* __restrict__ x,
                                               uint32* __restrict__ xq,
                                               float* __restrict__ xscale) {
    const int t   = blockIdx.x;
    const int tid = threadIdx.x;
    const float4* row4 = (const float4*)(x + (size_t)t * K_IN);

    float4 v[4];
    float amax = 0.f;
#pragma unroll
    for (int j = 0; j < 4; ++j) {
        v[j] = row4[tid + j * 256];
        amax = fmaxf(amax, fmaxf(fmaxf(fabsf(v[j].x), fabsf(v[j].y)),
                                 fmaxf(fabsf(v[j].z), fabsf(v[j].w))));
    }
#pragma unroll
    for (int off = 32; off > 0; off >>= 1)
        amax = fmaxf(amax, __shfl_down(amax, off, 64));
    __shared__ float red[4];
    if ((tid & 63) == 0) red[tid >> 6] = amax;
    __syncthreads();
    amax = fmaxf(fmaxf(red[0], red[1]), fmaxf(red[2], red[3]));

    const float scale = fmaxf(amax, 1e-12f) / 448.0f;
    if (tid == 0) xscale[t] = scale;

    uint32* orow = xq + (size_t)t * (K_IN / 4);
#pragma unroll
    for (int j = 0; j < 4; ++j) {
        // correctly-rounded fp32 division matches the reference's x / x_scale
        float q0 = v[j].x / scale, q1 = v[j].y / scale;
        float q2 = v[j].z / scale, q3 = v[j].w / scale;
        orow[tid + j * 256] = (uint32)pack4_fp8(q0, q1, q2, q3);  // coalesced dword
    }
}

// ---------- kernel 2: fp8 quantization of W (scale applied inside GEMM) ----------
__global__ __launch_bounds__(256) void quant_w(const float* __restrict__ w,
                                               uint32* __restrict__ wq) {
    const size_t u = (size_t)blockIdx.x * 256 + threadIdx.x;  // dword index
    float4 v = ((const float4*)w)[u];
    wq[u] = (uint32)pack4_fp8(v.x, v.y, v.z, v.w);
}

// ---------- kernel 3: fp8 MX GEMM with Horner block-scale rescaling ----------
// A: [T][K] fp8 bytes, B: [O][K] fp8 bytes. C[t][o] = xs[t] * sum_kb s[o/128][kb] * (A.B)
// 128x128x128 tile, 4 waves 2x2, each wave 64x64 via 4x4 mfma_scale 16x16x128.
__global__ __launch_bounds__(256) void gemm_fp8(const unsigned char* __restrict__ A,
                                                const unsigned char* __restrict__ B,
                                                const float* __restrict__ sinv,
                                                const float* __restrict__ xscale,
                                                float* __restrict__ C) {
    constexpr int BM = 128, BN = 128, BK = 128;
    __shared__ unsigned char As[BM * BK];  // 16 KB; 16B chunk slot j of row r holds global chunk j^(r&7)
    __shared__ unsigned char Bs[BN * BK];  // 16 KB

    const int bn = blockIdx.x;          // o tile (48) == one o scale-block
    const int bm = blockIdx.y;          // token tile (64)
    const int tid  = threadIdx.x;
    const int lane = tid & 63;
    const int wv   = tid >> 6;
    const int wm   = (wv >> 1) * 64;
    const int wn   = (wv & 1) * 64;

    const unsigned char* Abase = A + (size_t)(bm * BM) * K_IN;
    const unsigned char* Bbase = B + (size_t)(bn * BN) * K_IN;
    const float* srow = sinv + bn * (K_IN / 128);

    f32x4 acc[4][4] = {};
    float s_prev = srow[0];

    for (int kb = 0; kb < K_IN / BK; ++kb) {
        const int k0 = kb * BK;
        // stage 16 KB A + 16 KB B. LDS dest linear in lane (wave-uniform base +
        // lane*16); swizzle applied on the GLOBAL source chunk index.
#pragma unroll
        for (int s = 0; s < 4; ++s) {
            int c  = s * 256 + tid;
            int r  = c >> 3;
            int kc = (c & 7) ^ (r & 7);
            load_lds_16(Abase + (size_t)r * K_IN + k0 + kc * 16, &As[c * 16]);
        }
#pragma unroll
        for (int s = 0; s < 4; ++s) {
            int c  = s * 256 + tid;
            int r  = c >> 3;
            int kc = (c & 7) ^ (r & 7);
            load_lds_16(Bbase + (size_t)r * K_IN + k0 + kc * 16, &Bs[c * 16]);
        }
        __syncthreads();

        // Horner rescale: keep acc in units of 1/s_cur
        const float s_cur = srow[kb];
        const float rr = s_prev / s_cur;   // == 1.0 exactly at kb==0
        s_prev = s_cur;
#pragma unroll
        for (int i = 0; i < 4; ++i)
#pragma unroll
            for (int j = 0; j < 4; ++j)
                acc[i][j] = acc[i][j] * rr;

        // fragments: lane holds row m=lane&15 (A) / col n=lane&15 (B),
        // k = (lane>>4)*32 + 0..31  -> two swizzled 16B LDS chunks
        union F { i32x8 v; int4 h[2]; } a[4], b[4];
        const int G2 = (lane >> 4) * 2;
#pragma unroll
        for (int i = 0; i < 4; ++i) {
            int r = wm + i * 16 + (lane & 15);
            a[i].h[0] = *(const int4*)&As[(r * 8 + (G2 ^ (r & 7))) * 16];
            a[i].h[1] = *(const int4*)&As[(r * 8 + ((G2 + 1) ^ (r & 7))) * 16];
        }
#pragma unroll
        for (int j = 0; j < 4; ++j) {
            int r = wn + j * 16 + (lane & 15);
            b[j].h[0] = *(const int4*)&Bs[(r * 8 + (G2 ^ (r & 7))) * 16];
            b[j].h[1] = *(const int4*)&Bs[(r * 8 + ((G2 + 1) ^ (r & 7))) * 16];
        }

#pragma unroll
        for (int i = 0; i < 4; ++i)
#pragma unroll
            for (int j = 0; j < 4; ++j)
                acc[i][j] = __builtin_amdgcn_mfma_scale_f32_16x16x128_f8f6f4(
                    a[i].v, b[j].v, acc[i][j],
                    0 /*cbsz: A=fp8 e4m3*/, 0 /*blgp: B=fp8 e4m3*/,
                    0, 0x7f7f7f7f,   // scale_a opsel, e8m0 scales = 1.0
                    0, 0x7f7f7f7f);  // scale_b
        __syncthreads();
    }

    // epilogue: D col=lane&15, row=(lane>>4)*4+reg; final scale = s_last * xs[token]
#pragma unroll
    for (int i = 0; i < 4; ++i) {
#pragma unroll
        for (int r = 0; r < 4; ++r) {
            int m_g = bm * BM + wm + i * 16 + (lane >> 4) * 4 + r;
            float f = xscale[m_g] * s_prev;
            float* crow = C + (size_t)m_g * O_OUT + bn * BN + wn;
#pragma unroll
            for (int j = 0; j < 4; ++j)
                crow[j * 16 + (lane & 15)] = acc[i][j][r] * f;
        }
    }
}

// ---------- launch ----------
extern "C" void kernel_launch(void* const* d_in, const int* in_sizes, int n_in,
                              void* d_out, int out_size, void* d_ws, size_t ws_size,
                              hipStream_t stream) {
    const float* x    = (const float*)d_in[0];
    const float* w    = (const float*)d_in[1];
    const float* sinv = (const float*)d_in[2];
    float* out = (float*)d_out;

    char* ws = (char*)d_ws;
    uint32* xq = (uint32*)ws;                                   // 32 MB (fp8 bytes)
    uint32* wq = (uint32*)(ws + (size_t)T_TOK * K_IN);          // 24 MB
    float* xscale = (float*)(ws + (size_t)T_TOK * K_IN
                                + (size_t)O_OUT * K_IN);        // 32 KB

    quant_x<<<T_TOK, 256, 0, stream>>>(x, xq, xscale);
    quant_w<<<(O_OUT * K_IN) / (4 * 256), 256, 0, stream>>>(w, wq);
    dim3 grid(O_OUT / 128, T_TOK / 128);   // (48, 64)
    gemm_fp8<<<grid, 256, 0, stream>>>((const unsigned char*)xq,
                                       (const unsigned char*)wq,
                                       sinv, xscale, out);
}